// Round 30
// baseline (317.864 us; speedup 1.0000x reference)
//
#include <hip/hip_runtime.h>
#include <hip/hip_bf16.h>
#include <math.h>

#define D_MODEL 1024
#define NHEADS  16
#define DHEAD   64
#define D_HID   4096

typedef __attribute__((ext_vector_type(8))) short short8;   // 8 bf16 = 4 VGPR
typedef __attribute__((ext_vector_type(4))) short short4v;
typedef __attribute__((ext_vector_type(4))) float f32x4;
typedef __attribute__((ext_vector_type(16))) float f32x16;  // 32x32 mfma acc
typedef __attribute__((ext_vector_type(2))) unsigned uint2v;

#define QSCALE_F 0.04508422002778011f      /* log2(e)/32 : exp2-domain scores */
#define MASK_T   4.5084220e8f              /* 1e10 * log2(e)/32 */

__device__ inline short f2bs(float x) {
    union { __hip_bfloat16 b; short s; } u;
    u.b = __float2bfloat16(x);
    return u.s;
}
__device__ inline float bs2f(ushort s) {
    union { unsigned u; float f; } v; v.u = ((unsigned)s) << 16; return v.f;
}
// HW packed f32->bf16 (RNE), 1 instr for 2 values (no builtin on gfx950)
__device__ inline unsigned cvtpk(float lo, float hi) {
    unsigned r;
    asm("v_cvt_pk_bf16_f32 %0, %1, %2" : "=v"(r) : "v"(lo), "v"(hi));
    return r;
}
__device__ inline short8 pack8(float4 x, float4 y) {
    short8 v;
    v[0] = f2bs(x.x); v[1] = f2bs(x.y); v[2] = f2bs(x.z); v[3] = f2bs(x.w);
    v[4] = f2bs(y.x); v[5] = f2bs(y.y); v[6] = f2bs(y.z); v[7] = f2bs(y.w);
    return v;
}
// async global->LDS, 16B per lane; dest = wave-uniform base + lane*16
typedef const unsigned __attribute__((address_space(1))) gu32;
typedef unsigned __attribute__((address_space(3))) lu32;
__device__ inline void gload16(const void* g, void* l) {
    __builtin_amdgcn_global_load_lds((gu32*)g, (lu32*)l, 16, 0, 0);
}
// XOR swizzle for [row][128B] LDS tiles: logical chunk c of row r lives at
// physical chunk c^(r&7). Matches the gload pre-swizzled source mapping.
__device__ inline int swz(int r, int byteInRow) {
    return (r * 128 + byteInRow) ^ ((r & 7) << 4);
}

// ---------------------------------------------------------------------------
// Weight cast/pack: 10 fp32 weights -> one bf16 arena (16M elems).
// ---------------------------------------------------------------------------
struct WP { const float* p[10]; };
__global__ __launch_bounds__(256) void cast_weights(WP wp, short* __restrict__ dst) {
    const int n8 = (16 << 20) / 8;
    for (int i = blockIdx.x * 256 + threadIdx.x; i < n8; i += gridDim.x * 256) {
        size_t e = (size_t)i * 8;
        int seg = (int)(e >> 20);
        const float* src;
        if (seg < 8)       src = wp.p[seg] + (e & ((1u << 20) - 1));
        else if (seg < 12) src = wp.p[8] + (e - ((size_t)8 << 20));
        else               src = wp.p[9] + (e - ((size_t)12 << 20));
        float4 a = *(const float4*)src;
        float4 b = *(const float4*)(src + 4);
        *(short8*)(dst + e) = pack8(a, b);
    }
}

__global__ __launch_bounds__(256) void cast_f2b(const float* __restrict__ in,
                                                short* __restrict__ out, int n8) {
    for (int i = blockIdx.x * 256 + threadIdx.x; i < n8; i += gridDim.x * 256) {
        float4 a = *(const float4*)(in + (size_t)i * 8);
        float4 b = *(const float4*)(in + (size_t)i * 8 + 4);
        *(short8*)(out + (size_t)i * 8) = pack8(a, b);
    }
}

// ---------------------------------------------------------------------------
// bf16 MFMA GEMM: C[M,N] = A[M,K] * B[N,K]^T.  128x128 tile, BK=64,
// 8 WAVES (512 threads, 2M x 4N wave grid, 64x32 per wave) -> 16 waves/CU.
// 2-phase double-buffered staging; chunk-XOR swizzle via pre-swizzled source.
// OM: 0 = fp32 out, 1 = bf16 out,
//     2 = bf16 routed (QKV split) with FUSED V-TRANSPOSE: segments (col>>10)
//         < vseg go linear to Cb + seg*routeElems; segment == vseg is V and
//         is written transposed into Vt[bh][t][d=64][kv=64] (passed via Cf).
//         Each thread's 4 acc rows = 4 consecutive kv at fixed d -> one 8B
//         store. Replaces the standalone v_prep kernel (saves 16MB L2 trip).
//     3 = SPLIT-K dual: blockIdx.z = k-half; z==0 -> Cf fp32 (+bias),
//         z==1 -> Cb bf16 partial. K arg = sub-K; combine fused in add_ln.
// Bijective XCD swizzle on flattened block id (x*y grids %8 == 0).
// ---------------------------------------------------------------------------
template<int OM, bool BIAS, bool RELU, bool ACCUM>
__global__ __launch_bounds__(512) void gemm_mfma(
    const short* __restrict__ A, int lda,
    const short* __restrict__ Bm, int ldb,
    const float* __restrict__ bias,
    float* __restrict__ Cf, short* __restrict__ Cb, int ldc,
    int M, int N, int K, size_t routeElems, float qscale, int vseg)
{
    __shared__ short Als[2][128 * 64];
    __shared__ short Bls[2][128 * 64];

    const int tid = threadIdx.x, w = tid >> 6, l = tid & 63;
    const int l15 = l & 15, lhi = l >> 4;
    const int wr = w >> 2, wc = w & 3;          // 2M x 4N wave grid

    const int kh = (OM == 3) ? blockIdx.z : 0;
    if (OM == 3) {
        A  += (size_t)kh * K;
        Bm += (size_t)kh * K;
    }

    // XCD-aware block swizzle (T1), per z-slice
    const unsigned nwg  = gridDim.x * gridDim.y;
    const unsigned wgid = blockIdx.y * gridDim.x + blockIdx.x;
    const unsigned cpx  = nwg >> 3;                       // nwg % 8 == 0
    const unsigned sid  = (wgid & 7) * cpx + (wgid >> 3);
    const int bm = (int)(sid / gridDim.x) * 128;
    const int bn = (int)(sid % gridDim.x) * 128;

    // staging: 512 lanes x 16B = 64 rows of 128B per issue; 2 issues per tile.
    const int srow = w * 8 + (l >> 3);
    const int schk = ((l & 7) ^ (l >> 3)) * 8;            // pre-swizzled chunk

    f32x4 acc[4][2] = {};

    // prologue: stage k-tile 0 into buf 0
    #pragma unroll
    for (int i = 0; i < 2; ++i) {
        const short* ga = A  + (size_t)(bm + i * 64 + srow) * lda + schk;
        const short* gb = Bm + (size_t)(bn + i * 64 + srow) * ldb + schk;
        gload16(ga, &Als[0][i * 4096 + w * 512 + l * 8]);
        gload16(gb, &Bls[0][i * 4096 + w * 512 + l * 8]);
    }
    __syncthreads();

    const int nIter = K >> 6;
    int cur = 0;
    for (int it = 0; it < nIter; ++it) {
        // ---- issue NEXT tile's loads into the other buffer (prefetch) ----
        if (it + 1 < nIter) {
            const int k1 = (it + 1) << 6;
            #pragma unroll
            for (int i = 0; i < 2; ++i) {
                const short* ga = A  + (size_t)(bm + i * 64 + srow) * lda + k1 + schk;
                const short* gb = Bm + (size_t)(bn + i * 64 + srow) * ldb + k1 + schk;
                gload16(ga, &Als[cur ^ 1][i * 4096 + w * 512 + l * 8]);
                gload16(gb, &Bls[cur ^ 1][i * 4096 + w * 512 + l * 8]);
            }
        }

        // ---- compute current tile (wave: rows wr*64..+64, cols wc*32..+32) ----
        short8 af[4][2], bf[2][2];
        #pragma unroll
        for (int m = 0; m < 4; ++m) {
            const int row = wr * 64 + m * 16 + l15;
            #pragma unroll
            for (int kk = 0; kk < 2; ++kk)
                af[m][kk] = *(const short8*)&Als[cur][row * 64 + (((kk * 4 + lhi) ^ (l15 & 7)) * 8)];
        }
        #pragma unroll
        for (int n = 0; n < 2; ++n) {
            const int row = wc * 32 + n * 16 + l15;
            #pragma unroll
            for (int kk = 0; kk < 2; ++kk)
                bf[n][kk] = *(const short8*)&Bls[cur][row * 64 + (((kk * 4 + lhi) ^ (l15 & 7)) * 8)];
        }
        __builtin_amdgcn_s_setprio(1);
        #pragma unroll
        for (int kk = 0; kk < 2; ++kk)
            #pragma unroll
            for (int m = 0; m < 4; ++m)
                #pragma unroll
                for (int n = 0; n < 2; ++n)
                    acc[m][n] = __builtin_amdgcn_mfma_f32_16x16x32_bf16(af[m][kk], bf[n][kk], acc[m][n], 0, 0, 0);
        __builtin_amdgcn_s_setprio(0);

        __syncthreads();   // drains vmcnt (prefetch landed) + buffer safety
        cur ^= 1;
    }

    #pragma unroll
    for (int n = 0; n < 2; ++n) {
        const int col = bn + wc * 32 + n * 16 + l15;
        float bv = 0.f;
        if (BIAS && (OM != 3 || kh == 0)) bv = bias[col];
        const float sc = (OM == 2) ? (col < 1024 ? qscale : 1.f) : qscale;
        #pragma unroll
        for (int m = 0; m < 4; ++m) {
            const int row0 = bm + wr * 64 + m * 16 + lhi * 4;
            if (OM == 2 && (col >> 10) == vseg) {
                // ---- V: transposed store into Vt[bh][t][d][kv] (8B vector) ----
                const int s = row0 & 2047, bb = row0 >> 11;    // S=2048, B=2
                const int vcol = col & 1023;
                short* vt = (short*)Cf;
                const size_t dst = ((size_t)((bb * 16 + (vcol >> 6)) * 32 + (s >> 6))) * 4096
                                 + (size_t)(vcol & 63) * 64 + (s & 63);
                short4v sv;
                #pragma unroll
                for (int i = 0; i < 4; ++i) sv[i] = f2bs(acc[m][n][i]);
                *(short4v*)(vt + dst) = sv;
                continue;
            }
            #pragma unroll
            for (int i = 0; i < 4; ++i) {
                float v = acc[m][n][i] + bv;
                if (ACCUM) v += Cf[(size_t)(row0 + i) * ldc + col];
                if (RELU)  v = fmaxf(v, 0.f);
                v *= sc;
                if (OM == 0) {
                    Cf[(size_t)(row0 + i) * ldc + col] = v;
                } else if (OM == 1) {
                    Cb[(size_t)(row0 + i) * ldc + col] = f2bs(v);
                } else if (OM == 2) {
                    Cb[(size_t)(col >> 10) * routeElems +
                       (size_t)(row0 + i) * 1024 + (col & 1023)] = f2bs(v);
                } else {                     // OM == 3: split-K dual
                    if (kh == 0) Cf[(size_t)(row0 + i) * ldc + col] = v;
                    else         Cb[(size_t)(row0 + i) * ldc + col] = f2bs(v);
                }
            }
        }
    }
}

// ---------------------------------------------------------------------------
// attn_v18: v16 inner body (serial l_lane accumulation — R29's 4-way tree
// REVERTED: it perturbed the setprio-region schedule, −1.6 µs/dispatch) on
// top of the fused-V-transpose pipeline (no v_prep kernel).
// KVBLK=128 (two 64-kv tiles per barrier; K 16KB + V 16KB dbuf), gload
// staging with pre-swizzled source, ILP-2 subtile pairing, static-max exp2
// softmax, permlane32_swap P-exchange, fused normalize+store.
// CAUSAL uses the complement-pair load-balanced band map.
// ---------------------------------------------------------------------------
template<bool CAUSAL>
__global__ __launch_bounds__(256, 2) void attn_v18(
    const short* __restrict__ Qb, const short* __restrict__ Kr,
    const short* __restrict__ Vt, short* __restrict__ Out, int S)
{
    __shared__ __align__(16) char smem[2 * 32768];   // [buf][K 16K | V 16K]

    const int tid = threadIdx.x, w = tid >> 6, l = tid & 63;
    const int l31 = l & 31, hi = l >> 5;

    const unsigned wgid = blockIdx.x;        // grid = 512 x 1
    int bnd, bh;
    if (CAUSAL) {
        if (wgid < 256) { bh = (int)(wgid & 31); bnd = 15 - (int)(wgid >> 5); }
        else            { unsigned i = wgid - 256; bh = (int)(i & 31); bnd = (int)(i >> 5); }
    } else {
        const unsigned sid = (wgid & 7) * 64 + (wgid >> 3);   // bijective, 512%8==0
        bnd = (int)(sid & 15);
        bh  = (int)(sid >> 4);
    }
    const int b = bh >> 4, h = bh & 15;
    const int qw = bnd * 128 + w * 32;     // wave's first q row
    const int q  = qw + l31;

    const short* qp = Qb + ((size_t)(b * S + q)) * 1024 + h * 64 + hi * 8;
    short8 bq[4];
    #pragma unroll
    for (int dc = 0; dc < 4; ++dc) bq[dc] = *(const short8*)(qp + dc * 16);

    const short* kbase = Kr + ((size_t)b * S) * 1024 + h * 64;
    const short* vbase = Vt + (size_t)bh * ((S / 64) * 4096);

    f32x16 ot0 = {}, ot1 = {};
    float l_lane = 0.f;

    const int tMax = CAUSAL ? bnd : (S / 128 - 1);

    const int sro  = w * 32 + (l >> 3);
    const int schk = ((l & 7) ^ (l >> 3)) * 8;           // bf16 elems

    // prologue: stage block 0 into buf 0
    {
        char* Kls = smem;  char* Vls = smem + 16384;
        #pragma unroll
        for (int g = 0; g < 4; ++g) {
            gload16(kbase + (size_t)(sro + g * 8) * 1024 + schk, Kls + (size_t)w * 4096 + g * 1024);
            gload16(vbase + (size_t)(sro + g * 8) * 64   + schk, Vls + (size_t)w * 4096 + g * 1024);
        }
    }
    __syncthreads();

    int cur = 0;
    for (int t = 0; t <= tMax; ++t) {
        if (t + 1 <= tMax) {    // prefetch next 128-block into other buffer
            char* Kn = smem + (cur ^ 1) * 32768;
            char* Vn = Kn + 16384;
            #pragma unroll
            for (int g = 0; g < 4; ++g) {
                gload16(kbase + (size_t)((t + 1) * 128 + sro + g * 8) * 1024 + schk, Kn + (size_t)w * 4096 + g * 1024);
                gload16(vbase + (size_t)(t + 1) * 8192 + (size_t)(sro + g * 8) * 64 + schk, Vn + (size_t)w * 4096 + g * 1024);
            }
        }

        const char* Kls = smem + cur * 32768;
        const char* Vls = Kls + 16384;

        #pragma unroll
        for (int sp = 0; sp < 2; ++sp) {
            const int kv0p = t * 128 + sp * 64;
            if (CAUSAL && kv0p > qw + 31) break;   // pair fully masked

            // ---- QK^T both subtiles of this pair, 2 independent chains ----
            f32x16 st0 = {}, st1 = {};
            __builtin_amdgcn_s_setprio(1);
            #pragma unroll
            for (int dc = 0; dc < 4; ++dc) {
                short8 a0 = *(const short8*)(Kls + swz(sp * 64 + l31,      dc * 32 + hi * 16));
                short8 a1 = *(const short8*)(Kls + swz(sp * 64 + 32 + l31, dc * 32 + hi * 16));
                st0 = __builtin_amdgcn_mfma_f32_32x32x16_bf16(a0, bq[dc], st0, 0, 0, 0);
                st1 = __builtin_amdgcn_mfma_f32_32x32x16_bf16(a1, bq[dc], st1, 0, 0, 0);
            }
            __builtin_amdgcn_s_setprio(0);

            if (CAUSAL && kv0p + 31 > qw) {        // su0 (partially) masked
                #pragma unroll
                for (int r = 0; r < 16; ++r) {
                    int kv = kv0p + (r & 3) + 8 * (r >> 2) + 4 * hi;
                    if (kv > q) st0[r] -= MASK_T;
                }
            }
            if (CAUSAL && kv0p + 63 > qw) {        // su1 (partially/fully) masked
                #pragma unroll
                for (int r = 0; r < 16; ++r) {
                    int kv = kv0p + 32 + (r & 3) + 8 * (r >> 2) + 4 * hi;
                    if (kv > q) st1[r] -= MASK_T;
                }
            }

            union U { unsigned u[4]; short8 s; };
            U c00, c01, c10, c11;
            {   // ---- softmax + pack su0 (permlane32_swap exchange) ----
                float p[16];
                #pragma unroll
                for (int r = 0; r < 16; ++r) { p[r] = __builtin_amdgcn_exp2f(st0[r]); l_lane += p[r]; }
                unsigned wd[8];
                #pragma unroll
                for (int i = 0; i < 8; ++i) wd[i] = cvtpk(p[2 * i], p[2 * i + 1]);
                uint2v r0 = __builtin_amdgcn_permlane32_swap(wd[0], wd[2], false, false);
                uint2v r1 = __builtin_amdgcn_permlane32_swap(wd[1], wd[3], false, false);
                uint2v r2 = __builtin_amdgcn_permlane32_swap(wd[4], wd[6], false, false);
                uint2v r3 = __builtin_amdgcn_permlane32_swap(wd[5], wd[7], false, false);
                c00.u[0] = r0[0]; c00.u[2] = r0[1];
                c00.u[1] = r1[0]; c00.u[3] = r1[1];
                c01.u[0] = r2[0]; c01.u[2] = r2[1];
                c01.u[1] = r3[0]; c01.u[3] = r3[1];
            }
            {   // ---- softmax + pack su1 ----
                float p[16];
                #pragma unroll
                for (int r = 0; r < 16; ++r) { p[r] = __builtin_amdgcn_exp2f(st1[r]); l_lane += p[r]; }
                unsigned wd[8];
                #pragma unroll
                for (int i = 0; i < 8; ++i) wd[i] = cvtpk(p[2 * i], p[2 * i + 1]);
                uint2v r0 = __builtin_amdgcn_permlane32_swap(wd[0], wd[2], false, false);
                uint2v r1 = __builtin_amdgcn_permlane32_swap(wd[1], wd[3], false, false);
                uint2v r2 = __builtin_amdgcn_permlane32_swap(wd[4], wd[6], false, false);
                uint2v r3 = __builtin_amdgcn_permlane32_swap(wd[5], wd[7], false, false);
                c10.u[0] = r0[0]; c10.u[2] = r0[1];
                c10.u[1] = r1[0]; c10.u[3] = r1[1];
                c11.u[0] = r2[0]; c11.u[2] = r2[1];
                c11.u[1] = r3[0]; c11.u[3] = r3[1];
            }

            // ---- PV: pair sp lives in V sub-tile sp (8KB) ----
            const char* Vsp = Vls + sp * 8192;
            __builtin_amdgcn_s_setprio(1);
            short8 av;
            av  = *(const short8*)(Vsp + swz(l31,      hi * 16));
            ot0 = __builtin_amdgcn_mfma_f32_32x32x16_bf16(av, c00.s, ot0, 0, 0, 0);
            av  = *(const short8*)(Vsp + swz(32 + l31, hi * 16));
            ot1 = __builtin_amdgcn_mfma_f32_32x32x16_bf16(av, c00.s, ot1, 0, 0, 0);
            av  = *(const short8*)(Vsp + swz(l31,      32 + hi * 16));
            ot0 = __builtin_amdgcn_mfma_f32_32x32x16_bf16(av, c01.s, ot0, 0, 0, 0);
            av  = *(const short8*)(Vsp + swz(32 + l31, 32 + hi * 16));
            ot1 = __builtin_amdgcn_mfma_f32_32x32x16_bf16(av, c01.s, ot1, 0, 0, 0);
            av  = *(const short8*)(Vsp + swz(l31,      64 + hi * 16));
            ot0 = __builtin_amdgcn_mfma_f32_32x32x16_bf16(av, c10.s, ot0, 0, 0, 0);
            av  = *(const short8*)(Vsp + swz(32 + l31, 64 + hi * 16));
            ot1 = __builtin_amdgcn_mfma_f32_32x32x16_bf16(av, c10.s, ot1, 0, 0, 0);
            av  = *(const short8*)(Vsp + swz(l31,      96 + hi * 16));
            ot0 = __builtin_amdgcn_mfma_f32_32x32x16_bf16(av, c11.s, ot0, 0, 0, 0);
            av  = *(const short8*)(Vsp + swz(32 + l31, 96 + hi * 16));
            ot1 = __builtin_amdgcn_mfma_f32_32x32x16_bf16(av, c11.s, ot1, 0, 0, 0);
            __builtin_amdgcn_s_setprio(0);
        }

        __syncthreads();   // drains vmcnt (prefetch landed) + buffer safety
        cur ^= 1;
    }

    // ---- fused epilogue: normalize by row-sum l, store bf16 output ----
    const float l_tot = l_lane + __shfl_xor(l_lane, 32, 64);
    const float inv = 1.f / l_tot;
    short* orow = Out + ((size_t)(b * S + q)) * 1024 + h * 64;
    #pragma unroll
    for (int i = 0; i < 8; ++i) {
        int dbase = ((2 * i) & 3) + 8 * (i >> 1) + 4 * hi;
        *(unsigned*)(orow + dbase)      = cvtpk(ot0[2 * i] * inv, ot0[2 * i + 1] * inv);
        *(unsigned*)(orow + 32 + dbase) = cvtpk(ot1[2 * i] * inv, ot1[2 * i + 1] * inv);
    }
}

// ---------------------------------------------------------------------------
// y = LayerNorm(in1 + in2 [+ in3]), unbiased (N-1) std, /(std+eps).
// ---------------------------------------------------------------------------
template<bool IN1BF, bool OUTBF, bool P3>
__global__ __launch_bounds__(256) void add_ln(
    const void* __restrict__ in1, const float* __restrict__ in2,
    const short* __restrict__ in3,
    const float* __restrict__ gam, const float* __restrict__ bet,
    void* __restrict__ y)
{
    const int row = blockIdx.x;
    const int tid = threadIdx.x;
    const size_t off = (size_t)row * D_MODEL;

    float a0, a1, a2, a3;
    if (IN1BF) {
        short4v xs = ((const short4v*)((const short*)in1 + off))[tid];
        a0 = bs2f((ushort)xs[0]); a1 = bs2f((ushort)xs[1]);
        a2 = bs2f((ushort)xs[2]); a3 = bs2f((ushort)xs[3]);
    } else {
        float4 xv = ((const float4*)((const float*)in1 + off))[tid];
        a0 = xv.x; a1 = xv.y; a2 = xv.z; a3 = xv.w;
    }
    float4 rv = ((const float4*)(in2 + off))[tid];
    float v0 = a0 + rv.x, v1 = a1 + rv.y, v2 = a2 + rv.z, v3 = a3 + rv.w;
    if (P3) {
        short4v ps = ((const short4v*)(in3 + off))[tid];
        v0 += bs2f((ushort)ps[0]); v1 += bs2f((ushort)ps[1]);
        v2 += bs2f((ushort)ps[2]); v3 += bs2f((ushort)ps[3]);
    }

    float s  = v0 + v1 + v2 + v3;
    float ss = v0 * v0 + v1 * v1 + v2 * v2 + v3 * v3;

    __shared__ float sb[8];
    #pragma unroll
    for (int o = 32; o > 0; o >>= 1) {
        s  += __shfl_down(s, o, 64);
        ss += __shfl_down(ss, o, 64);
    }
    const int lane = tid & 63, w = tid >> 6;
    if (lane == 0) { sb[w] = s; sb[4 + w] = ss; }
    __syncthreads();
    float S  = sb[0] + sb[1] + sb[2] + sb[3];
    float SS = sb[4] + sb[5] + sb[6] + sb[7];

    float mean = S * (1.f / D_MODEL);
    float var_sum = SS - S * mean;
    float stdv = sqrtf(var_sum * (1.f / (D_MODEL - 1)));
    float inv = 1.f / (stdv + 1e-6f);

    float4 gv = ((const float4*)gam)[tid];
    float4 bv = ((const float4*)bet)[tid];
    float o0 = gv.x * (v0 - mean) * inv + bv.x;
    float o1 = gv.y * (v1 - mean) * inv + bv.y;
    float o2 = gv.z * (v2 - mean) * inv + bv.z;
    float o3 = gv.w * (v3 - mean) * inv + bv.w;
    if (OUTBF) {
        short4v ov; ov[0] = f2bs(o0); ov[1] = f2bs(o1); ov[2] = f2bs(o2); ov[3] = f2bs(o3);
        ((short4v*)((short*)y + off))[tid] = ov;
    } else {
        ((float4*)((float*)y + off))[tid] = make_float4(o0, o1, o2, o3);
    }
}

// ---------------------------------------------------------------------------
extern "C" void kernel_launch(void* const* d_in, const int* in_sizes, int n_in,
                              void* d_out, int out_size, void* d_ws, size_t ws_size,
                              hipStream_t stream)
{
    const float* x     = (const float*)d_in[0];
    const float* enc   = (const float*)d_in[1];
    WP wp;
    for (int i = 0; i < 8; ++i) wp.p[i] = (const float*)d_in[2 + i];
    wp.p[8] = (const float*)d_in[10];   // ff_w1
    wp.p[9] = (const float*)d_in[12];   // ff_w2
    const float* ff_b1 = (const float*)d_in[11];
    const float* ff_b2 = (const float*)d_in[13];
    const float* ln1_g = (const float*)d_in[14];
    const float* ln1_b = (const float*)d_in[15];
    const float* ln2_g = (const float*)d_in[16];
    const float* ln2_b = (const float*)d_in[17];
    const float* ln3_g = (const float*)d_in[18];
    const float* ln3_b = (const float*)d_in[19];
    float* out = (float*)d_out;

    const int Bn = 2, S = 2048, M = Bn * S;
    const size_t MB = 1u << 20;
    char* ws = (char*)d_ws;
    short* Wb   = (short*)(ws);                 // [0,32MB) bf16 weights
    short* p32  = (short*)(ws + 32 * MB);       // xb / saOut / h1b / ff2-partial1
    short* p40  = (short*)(ws + 40 * MB);       // Qb / h2b
    short* p48  = (short*)(ws + 48 * MB);       // K raw / wo-partial1 ; FFN t [48,80)
    short* p56  = (short*)(ws + 56 * MB);       // caOut
    short* p64  = (short*)(ws + 64 * MB);       // encb
    short* p72  = (short*)(ws + 72 * MB);       // V^T tiles (written by GEMM epilogue)
    float* f0   = (float*)(ws + 80 * MB);       // fp32 partial0

    short* tbuf = p48;                          // FFN t: [48,80), 32 MB

    const size_t RT = 4 * MB;
    const short* W_saqkv = Wb;
    const short* W_sawo  = Wb + 3 * MB;
    const short* W_caq   = Wb + 4 * MB;
    const short* W_cakv  = Wb + 5 * MB;
    const short* W_cawo  = Wb + 7 * MB;
    const short* W_ff1   = Wb + 8 * MB;
    const short* W_ff2   = Wb + 12 * MB;

    dim3 blk(256);
    dim3 blk512(512);
    dim3 g_qkv(3072 / 128, M / 128);            // 768 blocks
    dim3 g_kv(2048 / 128, M / 128);             // 512
    dim3 g_n1k(1024 / 128, M / 128);            // 256 (ca_q only)
    dim3 g_spl(1024 / 128, M / 128, 2);         // 512 (split-K dual)
    dim3 g_ff1(4096 / 128, M / 128);            // 1024
    dim3 g_attn(512);                           // 4-wave blocks, 128-row bands
    dim3 g_ln(M);

    // ---- input casts (all depend only on kernel inputs; run up front) ----
    cast_weights<<<2048, blk, 0, stream>>>(wp, Wb);
    cast_f2b<<<2048, blk, 0, stream>>>(x, p32, (M * D_MODEL) / 8);
    cast_f2b<<<2048, blk, 0, stream>>>(enc, p64, (M * D_MODEL) / 8);

    // ---- self-attention (causal); Q pre-scaled by log2e/32 in GEMM;
    //      V written transposed into p72 by the epilogue (vseg=2) ----
    gemm_mfma<2,false,false,false><<<g_qkv, blk512, 0, stream>>>(p32, 1024, W_saqkv, 1024, nullptr, (float*)p72, p40, 1024, M, 3072, 1024, RT, QSCALE_F, 2);
    attn_v18<true><<<g_attn, blk, 0, stream>>>(p40, p48, p72, p32, S);    // out->p32 (xb dead)
    // sa_wo split-K: z0 -> f0 fp32, z1 -> p48 bf16 (K raw dead)
    gemm_mfma<3,false,false,false><<<g_spl, blk512, 0, stream>>>(p32, 1024, W_sawo, 1024, nullptr, f0, p48, 1024, M, 1024, 512, 0, 1.f, 99);
    add_ln<false,true,true><<<g_ln, blk, 0, stream>>>(x, f0, p48, ln1_g, ln1_b, p32);   // h1b

    // ---- cross-attention (encb cast in prologue); V transposed (vseg=1) ----
    gemm_mfma<2,false,false,false><<<g_kv, blk512, 0, stream>>>(p64, 1024, W_cakv, 1024, nullptr, (float*)p72, p48, 1024, M, 2048, 1024, RT, 1.f, 1);          // K->p48 V->p72
    gemm_mfma<1,false,false,false><<<g_n1k, blk512, 0, stream>>>(p32, 1024, W_caq, 1024, nullptr, nullptr, p40, 1024, M, 1024, 1024, 0, QSCALE_F, 99);          // Q->p40
    attn_v18<false><<<g_attn, blk, 0, stream>>>(p40, p48, p72, p56, S);   // out->p56
    // ca_wo split-K: z0 -> f0 fp32, z1 -> p48 bf16 (ca K raw dead)
    gemm_mfma<3,false,false,false><<<g_spl, blk512, 0, stream>>>(p56, 1024, W_cawo, 1024, nullptr, f0, p48, 1024, M, 1024, 512, 0, 1.f, 99);
    add_ln<true,true,true><<<g_ln, blk, 0, stream>>>(p32, f0, p48, ln2_g, ln2_b, p40);  // h2b

    // ---- FFN: t = relu(h2@w1.T+b1) [48,80); ff2 split-K z0->f0(+b2), z1->p32 ----
    gemm_mfma<1,true,true,false><<<g_ff1, blk512, 0, stream>>>(p40, 1024, W_ff1, 1024, ff_b1, nullptr, tbuf, 4096, M, 4096, 1024, 0, 1.f, 99);
    gemm_mfma<3,true,false,false><<<g_spl, blk512, 0, stream>>>(tbuf, 4096, W_ff2, 4096, ff_b2, f0, p32, 1024, M, 1024, 2048, 0, 1.f, 99);
    add_ln<true,false,true><<<g_ln, blk, 0, stream>>>(p40, f0, p32, ln3_g, ln3_b, out);
}

// Round 31
// 315.681 us; speedup vs baseline: 1.0069x; 1.0069x over previous
//
#include <hip/hip_runtime.h>
#include <hip/hip_bf16.h>
#include <math.h>

#define D_MODEL 1024
#define NHEADS  16
#define DHEAD   64
#define D_HID   4096

typedef __attribute__((ext_vector_type(8))) short short8;   // 8 bf16 = 4 VGPR
typedef __attribute__((ext_vector_type(4))) short short4v;
typedef __attribute__((ext_vector_type(4))) float f32x4;
typedef __attribute__((ext_vector_type(16))) float f32x16;  // 32x32 mfma acc
typedef __attribute__((ext_vector_type(2))) unsigned uint2v;

#define QSCALE_F 0.04508422002778011f      /* log2(e)/32 : exp2-domain scores */
#define MASK_T   4.5084220e8f              /* 1e10 * log2(e)/32 */

__device__ inline short f2bs(float x) {
    union { __hip_bfloat16 b; short s; } u;
    u.b = __float2bfloat16(x);
    return u.s;
}
__device__ inline float bs2f(ushort s) {
    union { unsigned u; float f; } v; v.u = ((unsigned)s) << 16; return v.f;
}
// HW packed f32->bf16 (RNE), 1 instr for 2 values (no builtin on gfx950)
__device__ inline unsigned cvtpk(float lo, float hi) {
    unsigned r;
    asm("v_cvt_pk_bf16_f32 %0, %1, %2" : "=v"(r) : "v"(lo), "v"(hi));
    return r;
}
__device__ inline short8 pack8(float4 x, float4 y) {
    short8 v;
    v[0] = f2bs(x.x); v[1] = f2bs(x.y); v[2] = f2bs(x.z); v[3] = f2bs(x.w);
    v[4] = f2bs(y.x); v[5] = f2bs(y.y); v[6] = f2bs(y.z); v[7] = f2bs(y.w);
    return v;
}
// async global->LDS, 16B per lane; dest = wave-uniform base + lane*16
typedef const unsigned __attribute__((address_space(1))) gu32;
typedef unsigned __attribute__((address_space(3))) lu32;
__device__ inline void gload16(const void* g, void* l) {
    __builtin_amdgcn_global_load_lds((gu32*)g, (lu32*)l, 16, 0, 0);
}
// XOR swizzle for [row][128B] LDS tiles: logical chunk c of row r lives at
// physical chunk c^(r&7). Matches the gload pre-swizzled source mapping.
__device__ inline int swz(int r, int byteInRow) {
    return (r * 128 + byteInRow) ^ ((r & 7) << 4);
}

// ---------------------------------------------------------------------------
// Weight cast/pack: 10 fp32 weights -> one bf16 arena (16M elems).
// ---------------------------------------------------------------------------
struct WP { const float* p[10]; };
__global__ __launch_bounds__(256) void cast_weights(WP wp, short* __restrict__ dst) {
    const int n8 = (16 << 20) / 8;
    for (int i = blockIdx.x * 256 + threadIdx.x; i < n8; i += gridDim.x * 256) {
        size_t e = (size_t)i * 8;
        int seg = (int)(e >> 20);
        const float* src;
        if (seg < 8)       src = wp.p[seg] + (e & ((1u << 20) - 1));
        else if (seg < 12) src = wp.p[8] + (e - ((size_t)8 << 20));
        else               src = wp.p[9] + (e - ((size_t)12 << 20));
        float4 a = *(const float4*)src;
        float4 b = *(const float4*)(src + 4);
        *(short8*)(dst + e) = pack8(a, b);
    }
}

__global__ __launch_bounds__(256) void cast_f2b(const float* __restrict__ in,
                                                short* __restrict__ out, int n8) {
    for (int i = blockIdx.x * 256 + threadIdx.x; i < n8; i += gridDim.x * 256) {
        float4 a = *(const float4*)(in + (size_t)i * 8);
        float4 b = *(const float4*)(in + (size_t)i * 8 + 4);
        *(short8*)(out + (size_t)i * 8) = pack8(a, b);
    }
}

// ---------------------------------------------------------------------------
// bf16 MFMA GEMM: C[M,N] = A[M,K] * B[N,K]^T.  128x128 tile, BK=64,
// 8 WAVES (512 threads, 2M x 4N wave grid, 64x32 per wave) -> 16 waves/CU.
// 2-phase double-buffered staging; chunk-XOR swizzle via pre-swizzled source.
// OM: 0 = fp32 out, 1 = bf16 out,
//     2 = bf16 routed (QKV split) with FUSED V-TRANSPOSE: segments (col>>10)
//         route linear to Cb + seg*routeElems; segment == vseg is V and is
//         written transposed into Vt[bh][t][d=64][kv=64] (passed via Cf).
//         Optional per-segment A select: blocks with bn < 1024 (Q segment)
//         read A from Aq instead of A — merges ca_q + ca_kv into one
//         dispatch (Q from h1b, K/V from encb). qscale applies to col<1024.
//     3 = SPLIT-K dual: blockIdx.z = k-half; z==0 -> Cf fp32 (+bias),
//         z==1 -> Cb bf16 partial. K arg = sub-K; combine fused in add_ln.
// Bijective XCD swizzle on flattened block id (x*y grids %8 == 0).
// ---------------------------------------------------------------------------
template<int OM, bool BIAS, bool RELU, bool ACCUM>
__global__ __launch_bounds__(512) void gemm_mfma(
    const short* __restrict__ A, int lda,
    const short* __restrict__ Bm, int ldb,
    const float* __restrict__ bias,
    float* __restrict__ Cf, short* __restrict__ Cb, int ldc,
    int M, int N, int K, size_t routeElems, float qscale, int vseg,
    const short* __restrict__ Aq)
{
    __shared__ short Als[2][128 * 64];
    __shared__ short Bls[2][128 * 64];

    const int tid = threadIdx.x, w = tid >> 6, l = tid & 63;
    const int l15 = l & 15, lhi = l >> 4;
    const int wr = w >> 2, wc = w & 3;          // 2M x 4N wave grid

    const int kh = (OM == 3) ? blockIdx.z : 0;
    if (OM == 3) {
        A  += (size_t)kh * K;
        Bm += (size_t)kh * K;
    }

    // XCD-aware block swizzle (T1), per z-slice
    const unsigned nwg  = gridDim.x * gridDim.y;
    const unsigned wgid = blockIdx.y * gridDim.x + blockIdx.x;
    const unsigned cpx  = nwg >> 3;                       // nwg % 8 == 0
    const unsigned sid  = (wgid & 7) * cpx + (wgid >> 3);
    const int bm = (int)(sid / gridDim.x) * 128;
    const int bn = (int)(sid % gridDim.x) * 128;

    // per-segment A select (merged ca-QKV: Q reads h1b, K/V read encb)
    if (OM == 2 && Aq != nullptr && bn < 1024) A = Aq;

    // staging: 512 lanes x 16B = 64 rows of 128B per issue; 2 issues per tile.
    const int srow = w * 8 + (l >> 3);
    const int schk = ((l & 7) ^ (l >> 3)) * 8;            // pre-swizzled chunk

    f32x4 acc[4][2] = {};

    // prologue: stage k-tile 0 into buf 0
    #pragma unroll
    for (int i = 0; i < 2; ++i) {
        const short* ga = A  + (size_t)(bm + i * 64 + srow) * lda + schk;
        const short* gb = Bm + (size_t)(bn + i * 64 + srow) * ldb + schk;
        gload16(ga, &Als[0][i * 4096 + w * 512 + l * 8]);
        gload16(gb, &Bls[0][i * 4096 + w * 512 + l * 8]);
    }
    __syncthreads();

    const int nIter = K >> 6;
    int cur = 0;
    for (int it = 0; it < nIter; ++it) {
        // ---- issue NEXT tile's loads into the other buffer (prefetch) ----
        if (it + 1 < nIter) {
            const int k1 = (it + 1) << 6;
            #pragma unroll
            for (int i = 0; i < 2; ++i) {
                const short* ga = A  + (size_t)(bm + i * 64 + srow) * lda + k1 + schk;
                const short* gb = Bm + (size_t)(bn + i * 64 + srow) * ldb + k1 + schk;
                gload16(ga, &Als[cur ^ 1][i * 4096 + w * 512 + l * 8]);
                gload16(gb, &Bls[cur ^ 1][i * 4096 + w * 512 + l * 8]);
            }
        }

        // ---- compute current tile (wave: rows wr*64..+64, cols wc*32..+32) ----
        short8 af[4][2], bf[2][2];
        #pragma unroll
        for (int m = 0; m < 4; ++m) {
            const int row = wr * 64 + m * 16 + l15;
            #pragma unroll
            for (int kk = 0; kk < 2; ++kk)
                af[m][kk] = *(const short8*)&Als[cur][row * 64 + (((kk * 4 + lhi) ^ (l15 & 7)) * 8)];
        }
        #pragma unroll
        for (int n = 0; n < 2; ++n) {
            const int row = wc * 32 + n * 16 + l15;
            #pragma unroll
            for (int kk = 0; kk < 2; ++kk)
                bf[n][kk] = *(const short8*)&Bls[cur][row * 64 + (((kk * 4 + lhi) ^ (l15 & 7)) * 8)];
        }
        __builtin_amdgcn_s_setprio(1);
        #pragma unroll
        for (int kk = 0; kk < 2; ++kk)
            #pragma unroll
            for (int m = 0; m < 4; ++m)
                #pragma unroll
                for (int n = 0; n < 2; ++n)
                    acc[m][n] = __builtin_amdgcn_mfma_f32_16x16x32_bf16(af[m][kk], bf[n][kk], acc[m][n], 0, 0, 0);
        __builtin_amdgcn_s_setprio(0);

        __syncthreads();   // drains vmcnt (prefetch landed) + buffer safety
        cur ^= 1;
    }

    #pragma unroll
    for (int n = 0; n < 2; ++n) {
        const int col = bn + wc * 32 + n * 16 + l15;
        float bv = 0.f;
        if (BIAS && (OM != 3 || kh == 0)) bv = bias[col];
        const float sc = (OM == 2) ? (col < 1024 ? qscale : 1.f) : qscale;
        #pragma unroll
        for (int m = 0; m < 4; ++m) {
            const int row0 = bm + wr * 64 + m * 16 + lhi * 4;
            if (OM == 2 && (col >> 10) == vseg) {
                // ---- V: transposed store into Vt[bh][t][d][kv] (8B vector) ----
                const int s = row0 & 2047, bb = row0 >> 11;    // S=2048, B=2
                const int vcol = col & 1023;
                short* vt = (short*)Cf;
                const size_t dst = ((size_t)((bb * 16 + (vcol >> 6)) * 32 + (s >> 6))) * 4096
                                 + (size_t)(vcol & 63) * 64 + (s & 63);
                short4v sv;
                #pragma unroll
                for (int i = 0; i < 4; ++i) sv[i] = f2bs(acc[m][n][i]);
                *(short4v*)(vt + dst) = sv;
                continue;
            }
            #pragma unroll
            for (int i = 0; i < 4; ++i) {
                float v = acc[m][n][i] + bv;
                if (ACCUM) v += Cf[(size_t)(row0 + i) * ldc + col];
                if (RELU)  v = fmaxf(v, 0.f);
                v *= sc;
                if (OM == 0) {
                    Cf[(size_t)(row0 + i) * ldc + col] = v;
                } else if (OM == 1) {
                    Cb[(size_t)(row0 + i) * ldc + col] = f2bs(v);
                } else if (OM == 2) {
                    Cb[(size_t)(col >> 10) * routeElems +
                       (size_t)(row0 + i) * 1024 + (col & 1023)] = f2bs(v);
                } else {                     // OM == 3: split-K dual
                    if (kh == 0) Cf[(size_t)(row0 + i) * ldc + col] = v;
                    else         Cb[(size_t)(row0 + i) * ldc + col] = f2bs(v);
                }
            }
        }
    }
}

// ---------------------------------------------------------------------------
// attn_v18: serial l_lane accumulation, fused-V-transpose pipeline.
// KVBLK=128 (two 64-kv tiles per barrier; K 16KB + V 16KB dbuf), gload
// staging with pre-swizzled source, ILP-2 subtile pairing, static-max exp2
// softmax, permlane32_swap P-exchange, fused normalize+store.
// CAUSAL uses the complement-pair load-balanced band map.
// ---------------------------------------------------------------------------
template<bool CAUSAL>
__global__ __launch_bounds__(256, 2) void attn_v18(
    const short* __restrict__ Qb, const short* __restrict__ Kr,
    const short* __restrict__ Vt, short* __restrict__ Out, int S)
{
    __shared__ __align__(16) char smem[2 * 32768];   // [buf][K 16K | V 16K]

    const int tid = threadIdx.x, w = tid >> 6, l = tid & 63;
    const int l31 = l & 31, hi = l >> 5;

    const unsigned wgid = blockIdx.x;        // grid = 512 x 1
    int bnd, bh;
    if (CAUSAL) {
        if (wgid < 256) { bh = (int)(wgid & 31); bnd = 15 - (int)(wgid >> 5); }
        else            { unsigned i = wgid - 256; bh = (int)(i & 31); bnd = (int)(i >> 5); }
    } else {
        const unsigned sid = (wgid & 7) * 64 + (wgid >> 3);   // bijective, 512%8==0
        bnd = (int)(sid & 15);
        bh  = (int)(sid >> 4);
    }
    const int b = bh >> 4, h = bh & 15;
    const int qw = bnd * 128 + w * 32;     // wave's first q row
    const int q  = qw + l31;

    const short* qp = Qb + ((size_t)(b * S + q)) * 1024 + h * 64 + hi * 8;
    short8 bq[4];
    #pragma unroll
    for (int dc = 0; dc < 4; ++dc) bq[dc] = *(const short8*)(qp + dc * 16);

    const short* kbase = Kr + ((size_t)b * S) * 1024 + h * 64;
    const short* vbase = Vt + (size_t)bh * ((S / 64) * 4096);

    f32x16 ot0 = {}, ot1 = {};
    float l_lane = 0.f;

    const int tMax = CAUSAL ? bnd : (S / 128 - 1);

    const int sro  = w * 32 + (l >> 3);
    const int schk = ((l & 7) ^ (l >> 3)) * 8;           // bf16 elems

    // prologue: stage block 0 into buf 0
    {
        char* Kls = smem;  char* Vls = smem + 16384;
        #pragma unroll
        for (int g = 0; g < 4; ++g) {
            gload16(kbase + (size_t)(sro + g * 8) * 1024 + schk, Kls + (size_t)w * 4096 + g * 1024);
            gload16(vbase + (size_t)(sro + g * 8) * 64   + schk, Vls + (size_t)w * 4096 + g * 1024);
        }
    }
    __syncthreads();

    int cur = 0;
    for (int t = 0; t <= tMax; ++t) {
        if (t + 1 <= tMax) {    // prefetch next 128-block into other buffer
            char* Kn = smem + (cur ^ 1) * 32768;
            char* Vn = Kn + 16384;
            #pragma unroll
            for (int g = 0; g < 4; ++g) {
                gload16(kbase + (size_t)((t + 1) * 128 + sro + g * 8) * 1024 + schk, Kn + (size_t)w * 4096 + g * 1024);
                gload16(vbase + (size_t)(t + 1) * 8192 + (size_t)(sro + g * 8) * 64 + schk, Vn + (size_t)w * 4096 + g * 1024);
            }
        }

        const char* Kls = smem + cur * 32768;
        const char* Vls = Kls + 16384;

        #pragma unroll
        for (int sp = 0; sp < 2; ++sp) {
            const int kv0p = t * 128 + sp * 64;
            if (CAUSAL && kv0p > qw + 31) break;   // pair fully masked

            // ---- QK^T both subtiles of this pair, 2 independent chains ----
            f32x16 st0 = {}, st1 = {};
            __builtin_amdgcn_s_setprio(1);
            #pragma unroll
            for (int dc = 0; dc < 4; ++dc) {
                short8 a0 = *(const short8*)(Kls + swz(sp * 64 + l31,      dc * 32 + hi * 16));
                short8 a1 = *(const short8*)(Kls + swz(sp * 64 + 32 + l31, dc * 32 + hi * 16));
                st0 = __builtin_amdgcn_mfma_f32_32x32x16_bf16(a0, bq[dc], st0, 0, 0, 0);
                st1 = __builtin_amdgcn_mfma_f32_32x32x16_bf16(a1, bq[dc], st1, 0, 0, 0);
            }
            __builtin_amdgcn_s_setprio(0);

            if (CAUSAL && kv0p + 31 > qw) {        // su0 (partially) masked
                #pragma unroll
                for (int r = 0; r < 16; ++r) {
                    int kv = kv0p + (r & 3) + 8 * (r >> 2) + 4 * hi;
                    if (kv > q) st0[r] -= MASK_T;
                }
            }
            if (CAUSAL && kv0p + 63 > qw) {        // su1 (partially/fully) masked
                #pragma unroll
                for (int r = 0; r < 16; ++r) {
                    int kv = kv0p + 32 + (r & 3) + 8 * (r >> 2) + 4 * hi;
                    if (kv > q) st1[r] -= MASK_T;
                }
            }

            union U { unsigned u[4]; short8 s; };
            U c00, c01, c10, c11;
            {   // ---- softmax + pack su0 (permlane32_swap exchange) ----
                float p[16];
                #pragma unroll
                for (int r = 0; r < 16; ++r) { p[r] = __builtin_amdgcn_exp2f(st0[r]); l_lane += p[r]; }
                unsigned wd[8];
                #pragma unroll
                for (int i = 0; i < 8; ++i) wd[i] = cvtpk(p[2 * i], p[2 * i + 1]);
                uint2v r0 = __builtin_amdgcn_permlane32_swap(wd[0], wd[2], false, false);
                uint2v r1 = __builtin_amdgcn_permlane32_swap(wd[1], wd[3], false, false);
                uint2v r2 = __builtin_amdgcn_permlane32_swap(wd[4], wd[6], false, false);
                uint2v r3 = __builtin_amdgcn_permlane32_swap(wd[5], wd[7], false, false);
                c00.u[0] = r0[0]; c00.u[2] = r0[1];
                c00.u[1] = r1[0]; c00.u[3] = r1[1];
                c01.u[0] = r2[0]; c01.u[2] = r2[1];
                c01.u[1] = r3[0]; c01.u[3] = r3[1];
            }
            {   // ---- softmax + pack su1 ----
                float p[16];
                #pragma unroll
                for (int r = 0; r < 16; ++r) { p[r] = __builtin_amdgcn_exp2f(st1[r]); l_lane += p[r]; }
                unsigned wd[8];
                #pragma unroll
                for (int i = 0; i < 8; ++i) wd[i] = cvtpk(p[2 * i], p[2 * i + 1]);
                uint2v r0 = __builtin_amdgcn_permlane32_swap(wd[0], wd[2], false, false);
                uint2v r1 = __builtin_amdgcn_permlane32_swap(wd[1], wd[3], false, false);
                uint2v r2 = __builtin_amdgcn_permlane32_swap(wd[4], wd[6], false, false);
                uint2v r3 = __builtin_amdgcn_permlane32_swap(wd[5], wd[7], false, false);
                c10.u[0] = r0[0]; c10.u[2] = r0[1];
                c10.u[1] = r1[0]; c10.u[3] = r1[1];
                c11.u[0] = r2[0]; c11.u[2] = r2[1];
                c11.u[1] = r3[0]; c11.u[3] = r3[1];
            }

            // ---- PV: pair sp lives in V sub-tile sp (8KB) ----
            const char* Vsp = Vls + sp * 8192;
            __builtin_amdgcn_s_setprio(1);
            short8 av;
            av  = *(const short8*)(Vsp + swz(l31,      hi * 16));
            ot0 = __builtin_amdgcn_mfma_f32_32x32x16_bf16(av, c00.s, ot0, 0, 0, 0);
            av  = *(const short8*)(Vsp + swz(32 + l31, hi * 16));
            ot1 = __builtin_amdgcn_mfma_f32_32x32x16_bf16(av, c00.s, ot1, 0, 0, 0);
            av  = *(const short8*)(Vsp + swz(l31,      32 + hi * 16));
            ot0 = __builtin_amdgcn_mfma_f32_32x32x16_bf16(av, c01.s, ot0, 0, 0, 0);
            av  = *(const short8*)(Vsp + swz(32 + l31, 32 + hi * 16));
            ot1 = __builtin_amdgcn_mfma_f32_32x32x16_bf16(av, c01.s, ot1, 0, 0, 0);
            av  = *(const short8*)(Vsp + swz(l31,      64 + hi * 16));
            ot0 = __builtin_amdgcn_mfma_f32_32x32x16_bf16(av, c10.s, ot0, 0, 0, 0);
            av  = *(const short8*)(Vsp + swz(32 + l31, 64 + hi * 16));
            ot1 = __builtin_amdgcn_mfma_f32_32x32x16_bf16(av, c10.s, ot1, 0, 0, 0);
            av  = *(const short8*)(Vsp + swz(l31,      96 + hi * 16));
            ot0 = __builtin_amdgcn_mfma_f32_32x32x16_bf16(av, c11.s, ot0, 0, 0, 0);
            av  = *(const short8*)(Vsp + swz(32 + l31, 96 + hi * 16));
            ot1 = __builtin_amdgcn_mfma_f32_32x32x16_bf16(av, c11.s, ot1, 0, 0, 0);
            __builtin_amdgcn_s_setprio(0);
        }

        __syncthreads();   // drains vmcnt (prefetch landed) + buffer safety
        cur ^= 1;
    }

    // ---- fused epilogue: normalize by row-sum l, store bf16 output ----
    const float l_tot = l_lane + __shfl_xor(l_lane, 32, 64);
    const float inv = 1.f / l_tot;
    short* orow = Out + ((size_t)(b * S + q)) * 1024 + h * 64;
    #pragma unroll
    for (int i = 0; i < 8; ++i) {
        int dbase = ((2 * i) & 3) + 8 * (i >> 1) + 4 * hi;
        *(unsigned*)(orow + dbase)      = cvtpk(ot0[2 * i] * inv, ot0[2 * i + 1] * inv);
        *(unsigned*)(orow + 32 + dbase) = cvtpk(ot1[2 * i] * inv, ot1[2 * i + 1] * inv);
    }
}

// ---------------------------------------------------------------------------
// y = LayerNorm(in1 + in2 [+ in3]), unbiased (N-1) std, /(std+eps).
// ---------------------------------------------------------------------------
template<bool IN1BF, bool OUTBF, bool P3>
__global__ __launch_bounds__(256) void add_ln(
    const void* __restrict__ in1, const float* __restrict__ in2,
    const short* __restrict__ in3,
    const float* __restrict__ gam, const float* __restrict__ bet,
    void* __restrict__ y)
{
    const int row = blockIdx.x;
    const int tid = threadIdx.x;
    const size_t off = (size_t)row * D_MODEL;

    float a0, a1, a2, a3;
    if (IN1BF) {
        short4v xs = ((const short4v*)((const short*)in1 + off))[tid];
        a0 = bs2f((ushort)xs[0]); a1 = bs2f((ushort)xs[1]);
        a2 = bs2f((ushort)xs[2]); a3 = bs2f((ushort)xs[3]);
    } else {
        float4 xv = ((const float4*)((const float*)in1 + off))[tid];
        a0 = xv.x; a1 = xv.y; a2 = xv.z; a3 = xv.w;
    }
    float4 rv = ((const float4*)(in2 + off))[tid];
    float v0 = a0 + rv.x, v1 = a1 + rv.y, v2 = a2 + rv.z, v3 = a3 + rv.w;
    if (P3) {
        short4v ps = ((const short4v*)(in3 + off))[tid];
        v0 += bs2f((ushort)ps[0]); v1 += bs2f((ushort)ps[1]);
        v2 += bs2f((ushort)ps[2]); v3 += bs2f((ushort)ps[3]);
    }

    float s  = v0 + v1 + v2 + v3;
    float ss = v0 * v0 + v1 * v1 + v2 * v2 + v3 * v3;

    __shared__ float sb[8];
    #pragma unroll
    for (int o = 32; o > 0; o >>= 1) {
        s  += __shfl_down(s, o, 64);
        ss += __shfl_down(ss, o, 64);
    }
    const int lane = tid & 63, w = tid >> 6;
    if (lane == 0) { sb[w] = s; sb[4 + w] = ss; }
    __syncthreads();
    float S  = sb[0] + sb[1] + sb[2] + sb[3];
    float SS = sb[4] + sb[5] + sb[6] + sb[7];

    float mean = S * (1.f / D_MODEL);
    float var_sum = SS - S * mean;
    float stdv = sqrtf(var_sum * (1.f / (D_MODEL - 1)));
    float inv = 1.f / (stdv + 1e-6f);

    float4 gv = ((const float4*)gam)[tid];
    float4 bv = ((const float4*)bet)[tid];
    float o0 = gv.x * (v0 - mean) * inv + bv.x;
    float o1 = gv.y * (v1 - mean) * inv + bv.y;
    float o2 = gv.z * (v2 - mean) * inv + bv.z;
    float o3 = gv.w * (v3 - mean) * inv + bv.w;
    if (OUTBF) {
        short4v ov; ov[0] = f2bs(o0); ov[1] = f2bs(o1); ov[2] = f2bs(o2); ov[3] = f2bs(o3);
        ((short4v*)((short*)y + off))[tid] = ov;
    } else {
        ((float4*)((float*)y + off))[tid] = make_float4(o0, o1, o2, o3);
    }
}

// ---------------------------------------------------------------------------
extern "C" void kernel_launch(void* const* d_in, const int* in_sizes, int n_in,
                              void* d_out, int out_size, void* d_ws, size_t ws_size,
                              hipStream_t stream)
{
    const float* x     = (const float*)d_in[0];
    const float* enc   = (const float*)d_in[1];
    WP wp;
    for (int i = 0; i < 8; ++i) wp.p[i] = (const float*)d_in[2 + i];
    wp.p[8] = (const float*)d_in[10];   // ff_w1
    wp.p[9] = (const float*)d_in[12];   // ff_w2
    const float* ff_b1 = (const float*)d_in[11];
    const float* ff_b2 = (const float*)d_in[13];
    const float* ln1_g = (const float*)d_in[14];
    const float* ln1_b = (const float*)d_in[15];
    const float* ln2_g = (const float*)d_in[16];
    const float* ln2_b = (const float*)d_in[17];
    const float* ln3_g = (const float*)d_in[18];
    const float* ln3_b = (const float*)d_in[19];
    float* out = (float*)d_out;

    const int Bn = 2, S = 2048, M = Bn * S;
    const size_t MB = 1u << 20;
    char* ws = (char*)d_ws;
    short* Wb   = (short*)(ws);                 // [0,32MB) bf16 weights
    short* p32  = (short*)(ws + 32 * MB);       // xb / saOut / h1b / ff2-partial1
    short* p40  = (short*)(ws + 40 * MB);       // Qb / h2b
    short* p48  = (short*)(ws + 48 * MB);       // K raw / wo-partial1 ; FFN t [48,80)
    short* p56  = (short*)(ws + 56 * MB);       // caOut
    short* p64  = (short*)(ws + 64 * MB);       // encb
    short* p72  = (short*)(ws + 72 * MB);       // V^T tiles (written by GEMM epilogue)
    float* f0   = (float*)(ws + 80 * MB);       // fp32 partial0

    short* tbuf = p48;                          // FFN t: [48,80), 32 MB

    const size_t RT = 4 * MB;
    const short* W_saqkv = Wb;
    const short* W_sawo  = Wb + 3 * MB;
    const short* W_caqkv = Wb + 4 * MB;         // [ca_wq; ca_wk; ca_wv] contiguous
    const short* W_cawo  = Wb + 7 * MB;
    const short* W_ff1   = Wb + 8 * MB;
    const short* W_ff2   = Wb + 12 * MB;

    dim3 blk(256);
    dim3 blk512(512);
    dim3 g_qkv(3072 / 128, M / 128);            // 768 blocks (sa AND merged ca)
    dim3 g_spl(1024 / 128, M / 128, 2);         // 512 (split-K dual)
    dim3 g_ff1(4096 / 128, M / 128);            // 1024
    dim3 g_attn(512);                           // 4-wave blocks, 128-row bands
    dim3 g_ln(M);

    // ---- input casts (all depend only on kernel inputs; run up front) ----
    cast_weights<<<2048, blk, 0, stream>>>(wp, Wb);
    cast_f2b<<<2048, blk, 0, stream>>>(x, p32, (M * D_MODEL) / 8);
    cast_f2b<<<2048, blk, 0, stream>>>(enc, p64, (M * D_MODEL) / 8);

    // ---- self-attention (causal); Q pre-scaled by log2e/32 in GEMM;
    //      V written transposed into p72 by the epilogue (vseg=2) ----
    gemm_mfma<2,false,false,false><<<g_qkv, blk512, 0, stream>>>(p32, 1024, W_saqkv, 1024, nullptr, (float*)p72, p40, 1024, M, 3072, 1024, RT, QSCALE_F, 2, nullptr);
    attn_v18<true><<<g_attn, blk, 0, stream>>>(p40, p48, p72, p32, S);    // out->p32 (xb dead)
    // sa_wo split-K: z0 -> f0 fp32, z1 -> p48 bf16 (K raw dead)
    gemm_mfma<3,false,false,false><<<g_spl, blk512, 0, stream>>>(p32, 1024, W_sawo, 1024, nullptr, f0, p48, 1024, M, 1024, 512, 0, 1.f, 99, nullptr);
    add_ln<false,true,true><<<g_ln, blk, 0, stream>>>(x, f0, p48, ln1_g, ln1_b, p32);   // h1b

    // ---- cross-attention: MERGED QKV GEMM (Q from h1b via Aq, K/V from encb);
    //      Q->p40 (x qscale), K->p48, V->p72 transposed (vseg=2) ----
    gemm_mfma<2,false,false,false><<<g_qkv, blk512, 0, stream>>>(p64, 1024, W_caqkv, 1024, nullptr, (float*)p72, p40, 1024, M, 3072, 1024, RT, QSCALE_F, 2, p32);
    attn_v18<false><<<g_attn, blk, 0, stream>>>(p40, p48, p72, p56, S);   // out->p56
    // ca_wo split-K: z0 -> f0 fp32, z1 -> p48 bf16 (ca K raw dead)
    gemm_mfma<3,false,false,false><<<g_spl, blk512, 0, stream>>>(p56, 1024, W_cawo, 1024, nullptr, f0, p48, 1024, M, 1024, 512, 0, 1.f, 99, nullptr);
    add_ln<true,true,true><<<g_ln, blk, 0, stream>>>(p32, f0, p48, ln2_g, ln2_b, p40);  // h2b

    // ---- FFN: t = relu(h2@w1.T+b1) [48,80); ff2 split-K z0->f0(+b2), z1->p32 ----
    gemm_mfma<1,true,true,false><<<g_ff1, blk512, 0, stream>>>(p40, 1024, W_ff1, 1024, ff_b1, nullptr, tbuf, 4096, M, 4096, 1024, 0, 1.f, 99, nullptr);
    gemm_mfma<3,true,false,false><<<g_spl, blk512, 0, stream>>>(tbuf, 4096, W_ff2, 4096, ff_b2, f0, p32, 1024, M, 1024, 2048, 0, 1.f, 99, nullptr);
    add_ln<true,false,true><<<g_ln, blk, 0, stream>>>(p40, f0, p32, ln3_g, ln3_b, out);
}